// Round 17
// baseline (3554.393 us; speedup 1.0000x reference)
//
#include <hip/hip_runtime.h>
#include <hip/hip_bf16.h>

typedef short bf16x4 __attribute__((ext_vector_type(4)));
typedef short bf16x8 __attribute__((ext_vector_type(8)));
typedef float f32x4 __attribute__((ext_vector_type(4)));
typedef __hip_bfloat16 bf16;
typedef unsigned long long ull;

#define NEGV -10000.0f

// Problem dims: B=64, T=256, E=300, H=500, K=64(tags), V=32000
// Padded: Ep=320, Hp=512, layer-1 input 2*Hp=1024, gate width 4096 = 2dir*4gate*512

__device__ __forceinline__ float sigm(float v) { return 1.0f / (1.0f + __expf(-v)); }
__device__ __forceinline__ float tanh_(float v) { float e = __expf(2.0f * v); return 1.0f - 2.0f / (e + 1.0f); }

// async global->LDS, 16B per lane: global src includes per-lane offset, LDS base wave-uniform
__device__ __forceinline__ void async_load16(const bf16* g, const char* l) {
  __builtin_amdgcn_global_load_lds((const __attribute__((address_space(1))) void*)g,
                                   (__attribute__((address_space(3))) void*)l, 16, 0, 0);
}

// ---------------- weight packing into MFMA fragment-linear layout ----------------
// B-frag layout: dst[((nt*Kt + kt)*64 + lane)*8 + u] = B[kt*32 + (lane>>4)*8 + u][nt*16 + (lane&15)]

__global__ __launch_bounds__(256) void pack_w0(const float* __restrict__ wf, const float* __restrict__ wb,
                                               bf16* __restrict__ dst) {
  int idx = blockIdx.x * 256 + threadIdx.x;            // 4096*320 = 1310720
  int u = idx & 7, lane = (idx >> 3) & 63, rem = idx >> 9;
  int kt = rem % 10, nt = rem / 10;
  int n = (nt << 4) + (lane & 15), k = (kt << 5) + ((lane >> 4) << 3) + u;
  int d = n >> 11, g = (n >> 9) & 3, j = n & 511;
  float v = 0.f;
  if (j < 500 && k < 300) v = (d ? wb : wf)[(g * 500 + j) * 300 + k];
  dst[idx] = __float2bfloat16(v);
}

// all 4 recurrent weight matrices in one launch (blockIdx.y selects)
__global__ __launch_bounds__(256) void pack_whh4(const float* __restrict__ w0f, const float* __restrict__ w0b,
                                                 const float* __restrict__ w1f, const float* __restrict__ w1b,
                                                 bf16* __restrict__ dst) {
  const int which = blockIdx.y;
  const float* w = which == 0 ? w0f : which == 1 ? w0b : which == 2 ? w1f : w1b;
  int idx = blockIdx.x * 256 + threadIdx.x;            // 2048*512 = 1048576 per matrix
  int u = idx & 7, lane = (idx >> 3) & 63, rem = idx >> 9;
  int kt = rem & 15, nt = rem >> 4;
  int n = (nt << 4) + (lane & 15), k = (kt << 5) + ((lane >> 4) << 3) + u;
  int g = n >> 9, j = n & 511;
  float v = 0.f;
  if (j < 500 && k < 500) v = w[(g * 500 + j) * 500 + k];
  dst[(size_t)which * 1048576 + idx] = __float2bfloat16(v);
}

__global__ __launch_bounds__(256) void pack_w1(const float* __restrict__ wf, const float* __restrict__ wb,
                                               bf16* __restrict__ dst) {
  int idx = blockIdx.x * 256 + threadIdx.x;            // 4096*1024 = 4194304
  int u = idx & 7, lane = (idx >> 3) & 63, rem = idx >> 9;
  int kt = rem & 31, nt = rem >> 5;
  int n = (nt << 4) + (lane & 15), k = (kt << 5) + ((lane >> 4) << 3) + u;
  int d = n >> 11, g = (n >> 9) & 3, j = n & 511;
  int kk = k & 511;
  int ks = (k < 512) ? kk : 500 + kk;
  float v = 0.f;
  if (j < 500 && kk < 500) v = (d ? wb : wf)[(g * 500 + j) * 1000 + ks];
  dst[idx] = __float2bfloat16(v);
}

__global__ __launch_bounds__(256) void pack_wout(const float* __restrict__ w, bf16* __restrict__ dst) {
  int idx = blockIdx.x * 256 + threadIdx.x;            // 4*32*512 = 65536
  int u = idx & 7, lane = (idx >> 3) & 63, rem = idx >> 9;
  int kt = rem & 31, nt = rem >> 5;
  int n = (nt << 4) + (lane & 15), k = (kt << 5) + ((lane >> 4) << 3) + u;
  int kk = k & 511;
  int ks = (k < 512) ? kk : 500 + kk;
  float v = 0.f;
  if (kk < 500) v = w[n * 1000 + ks];
  dst[idx] = __float2bfloat16(v);
}

// both layers' biases in one launch
__global__ __launch_bounds__(256) void pack_bias2(const float* __restrict__ b0f, const float* __restrict__ b0b,
                                                  const float* __restrict__ b1f, const float* __restrict__ b1b,
                                                  float* __restrict__ dst0, float* __restrict__ dst1) {
  int idx = blockIdx.x * 256 + threadIdx.x;
  int layer = idx >> 12, w = idx & 4095;
  int d = w >> 11, g = (w >> 9) & 3, j = w & 511;
  const float* src = layer ? (d ? b1b : b1f) : (d ? b0b : b0f);
  float v = (j < 500) ? src[g * 500 + j] : 0.f;
  (layer ? dst1 : dst0)[w] = v;
}

// ---------------- embedding gather -> bf16 [T*B][320] ----------------
__global__ __launch_bounds__(256) void embed_k(const int* __restrict__ x, const float* __restrict__ em,
                                               bf16* __restrict__ xs) {
  int idx = blockIdx.x * 256 + threadIdx.x;            // 16384*320
  int e = idx % 320;
  int row = idx / 320;
  int t = row >> 6, b = row & 63;
  float v = 0.f;
  if (e < 300) {
    int xv = x[b * 256 + t];
    v = em[(size_t)xv * 300 + e];
  }
  xs[idx] = __float2bfloat16(v);
}

// ---------------- MFMA GEMM: preP = A[16384][Kdim] @ Bfrag, epilogue scatters into
// per-thread-contiguous lstm consumption layout:
// preP[(((t*2+dir)*32+jb)*4+gate)*1024 + lane*16 + (mt*4+r)]
__global__ __launch_bounds__(256) void gemm_nt(const bf16* __restrict__ A, const bf16* __restrict__ Bf,
                                               bf16* __restrict__ C, int Kdim, int Kt) {
  const int lane = threadIdx.x & 63, wave = threadIdx.x >> 6;
  const int lr = lane & 15, lh = lane >> 4;
  const int mb = blockIdx.x * 64;
  const int ntb = blockIdx.y * 16 + wave * 4;
  f32x4 acc[4][4] = {};
  for (int kt = 0; kt < Kt; ++kt) {
    bf16x8 a[4], b[4];
#pragma unroll
    for (int mt = 0; mt < 4; ++mt)
      a[mt] = *(const bf16x8*)(A + (size_t)(mb + mt * 16 + lr) * Kdim + kt * 32 + lh * 8);
#pragma unroll
    for (int q = 0; q < 4; ++q)
      b[q] = *(const bf16x8*)(Bf + ((size_t)(ntb + q) * Kt + kt) * 512 + lane * 8);
#pragma unroll
    for (int mt = 0; mt < 4; ++mt)
#pragma unroll
      for (int q = 0; q < 4; ++q)
        acc[mt][q] = __builtin_amdgcn_mfma_f32_16x16x32_bf16(a[mt], b[q], acc[mt][q], 0, 0, 0);
  }
  const int t = blockIdx.x;  // rows [mb, mb+64) are exactly timestep t
#pragma unroll
  for (int q = 0; q < 4; ++q) {
    const int colbase = (ntb + q) * 16;
    const int dirq = colbase >> 11, gq = (colbase >> 9) & 3, jbq = (colbase >> 4) & 31;
    unsigned short vals[16];
#pragma unroll
    for (int mt = 0; mt < 4; ++mt)
#pragma unroll
      for (int r = 0; r < 4; ++r) {
        bf16 hb = __float2bfloat16(acc[mt][q][r]);
        vals[mt * 4 + r] = *(unsigned short*)&hb;
      }
    bf16* outp = C + ((((size_t)t * 2 + dirq) * 32 + jbq) * 4 + gq) * 1024 + lane * 16;
    *(bf16x8*)(outp) = *(const bf16x8*)(vals);
    *(bf16x8*)(outp + 8) = *(const bf16x8*)(vals + 8);
  }
}

// ---------------- lstm_wav: wave-autonomous, arrival-ordered pipeline, zero step barriers ----
// grid(32 jb, 2 dir), 256 thr = 4 waves; WAVE = part (16 batch rows), owns ALL 4 gates.
// MFMA C layout (row=lh*4+r, col=lr) is identical across the 4 gate MFMAs -> each thread holds
// i/f/g/o of its cells in acc[0..3] => cell fully in-register, c-state in 4 VGPRs, NO xch LDS,
// NO __syncthreads in the step loop. Weights (4 gates x 16 kt = 64KB) staged once into LDS
// (lane-linear, conflict-free, immune to reg-remat). h slices staged per arrival into per-wave
// private LDS (R14 rotation swizzle). Release: 4 sc0/sc1 h-stores -> per-wave vmcnt(0) ->
// ONE flag per wave (grain = R15, avoiding R16's paired-half-flag regression).
__global__ __launch_bounds__(256, 1) void lstm_wav(const bf16* __restrict__ preP, const bf16* __restrict__ whh,
                                                   const float* __restrict__ bias, bf16* __restrict__ hout,
                                                   unsigned int* __restrict__ flags) {
  const int tid = threadIdx.x, lane = tid & 63, wave = tid >> 6;  // wave == part
  const int lr = lane & 15, lh = lane >> 4;
  const int jb = blockIdx.x, dir = blockIdx.y, part = wave;
  unsigned int* flg = flags + (dir * 4 + part) * 64;
  unsigned int* myflg = flg + jb;
  __shared__ __align__(64) char wlds[4][16][1024];  // [gate][kt][16 rows x 64B] weights
  __shared__ __align__(64) char hsl[4][16][1024];   // [wave][kt][1KB] private h slices

  // stage this (jb,dir)'s weights once: wave w stages gate w's 16 kt-slices
  {
    const bf16* wsrc = whh + ((size_t)(dir * 128 + wave * 32 + jb) * 16) * 512 + lane * 8;
#pragma unroll
    for (int kt = 0; kt < 16; ++kt)
      async_load16(wsrc + kt * 512, &wlds[wave][kt][0] + lane * 16);
  }
  asm volatile("s_waitcnt vmcnt(0)" ::: "memory");
  __syncthreads();  // only barrier in the kernel (weights ready)

  float bb[4];
#pragma unroll
  for (int g = 0; g < 4; ++g) bb[g] = bias[dir * 2048 + g * 512 + jb * 16 + lr];

  // first-step pre prefetch: per gate, this thread's 4 values (8B load)
  unsigned short pf[4][4];
  {
    const int t0 = dir ? 255 : 0;
#pragma unroll
    for (int g = 0; g < 4; ++g)
      *(bf16x4*)pf[g] = *(const bf16x4*)(preP + ((((size_t)t0 * 2 + dir) * 32 + jb) * 4 + g) * 1024 +
                                         lane * 16 + part * 4);
  }

  float cst[4] = {0.f, 0.f, 0.f, 0.f};  // c-state in registers

  // staging geometry (R14-proven rotation): lane covers row=lane>>2, chunk lane&3, rotated src
  const int srow_st = lane >> 2, sq_st = lane & 3;
  const int gchunk = (sq_st + ((srow_st >> 1) & 3)) & 3;
  const int rp = (lh - ((lr >> 1) & 3)) & 3;  // LDS chunk holding global chunk lh for row lr

  for (int s = 0; s < 256; ++s) {
    const int t = dir ? 255 - s : s;
    f32x4 acc[4] = {};  // one accumulator per gate; same (row,col) ownership across gates
    if (s > 0) {
      const unsigned int tgt = (unsigned int)s;
      const int tp = dir ? t + 1 : t - 1;
      const bf16* hp = hout + (size_t)tp * 65536 + dir * 512 +
                       (size_t)(part * 16 + srow_st) * 1024 + gchunk * 8;
      unsigned int pend = 0xFFFFu;
      while (pend) {
        unsigned int v = __hip_atomic_load(flg + (lane & 31), __ATOMIC_RELAXED, __HIP_MEMORY_SCOPE_AGENT);
        unsigned int am = (unsigned int)__ballot((int)(v >= tgt));
        unsigned int ready = 0;
#pragma unroll
        for (int j = 0; j < 16; ++j) {
          if (((pend >> j) & 1u) && (((am >> (2 * j)) & 3u) == 3u)) {
            async_load16(hp + j * 32, &hsl[wave][j][0] + lane * 16);
            ready |= 1u << j;
          }
        }
        if (ready) {
          asm volatile("s_waitcnt vmcnt(0)" ::: "memory");
#pragma unroll
          for (int j = 0; j < 16; ++j) {
            if ((ready >> j) & 1u) {
              const bf16x8 afr = *(const bf16x8*)(&hsl[wave][j][0] + lr * 64 + rp * 16);
              acc[0] = __builtin_amdgcn_mfma_f32_16x16x32_bf16(
                  afr, *(const bf16x8*)(&wlds[0][j][0] + lane * 16), acc[0], 0, 0, 0);
              acc[1] = __builtin_amdgcn_mfma_f32_16x16x32_bf16(
                  afr, *(const bf16x8*)(&wlds[1][j][0] + lane * 16), acc[1], 0, 0, 0);
              acc[2] = __builtin_amdgcn_mfma_f32_16x16x32_bf16(
                  afr, *(const bf16x8*)(&wlds[2][j][0] + lane * 16), acc[2], 0, 0, 0);
              acc[3] = __builtin_amdgcn_mfma_f32_16x16x32_bf16(
                  afr, *(const bf16x8*)(&wlds[3][j][0] + lane * 16), acc[3], 0, 0, 0);
            }
          }
          pend &= ~ready;
        }
      }
    }
    // in-register LSTM cell: this thread owns rows part*16 + lh*4 + r, col jb*16 + lr
#pragma unroll
    for (int r = 0; r < 4; ++r) {
      bf16 p0, p1, p2, p3;
      *(unsigned short*)&p0 = pf[0][r];
      *(unsigned short*)&p1 = pf[1][r];
      *(unsigned short*)&p2 = pf[2][r];
      *(unsigned short*)&p3 = pf[3][r];
      float gi = acc[0][r] + bb[0] + __bfloat162float(p0);
      float gf = acc[1][r] + bb[1] + __bfloat162float(p1);
      float gg = acc[2][r] + bb[2] + __bfloat162float(p2);
      float go = acc[3][r] + bb[3] + __bfloat162float(p3);
      float cn = sigm(gf) * cst[r] + sigm(gi) * tanh_(gg);
      cst[r] = cn;
      bf16 hb = __float2bfloat16(sigm(go) * tanh_(cn));
      const bf16* addr = hout + ((size_t)t * 64 + part * 16 + lh * 4 + r) * 1024 + dir * 512 + jb * 16 + lr;
      unsigned int hv = *(unsigned short*)&hb;
      asm volatile("global_store_short %0, %1, off sc0 sc1" ::"v"(addr), "v"(hv) : "memory");
    }
    // wave-level release: vmcnt is per-wave; all this wave's h stores drained -> publish flag
    asm volatile("s_waitcnt vmcnt(0)" ::: "memory");
    if (lane == 0)
      __hip_atomic_store(myflg, (unsigned int)(s + 1), __ATOMIC_RELAXED, __HIP_MEMORY_SCOPE_AGENT);
    // prefetch next step's pre (hides under the next poll)
    if (s < 255) {
      const int tn = dir ? t - 1 : t + 1;
#pragma unroll
      for (int g = 0; g < 4; ++g)
        *(bf16x4*)pf[g] = *(const bf16x4*)(preP + ((((size_t)tn * 2 + dir) * 32 + jb) * 4 + g) * 1024 +
                                           lane * 16 + part * 4);
    }
  }
}

// ---------------- emit projection: emit[16384][64] = h1 @ WoutB + bout, masked ----------------
__global__ __launch_bounds__(256) void emit_k(const bf16* __restrict__ h1, const bf16* __restrict__ wo,
                                              const float* __restrict__ bout, const int* __restrict__ x,
                                              float* __restrict__ emit) {
  const int tid = threadIdx.x, lane = tid & 63, wave = tid >> 6;
  const int lr = lane & 15, lh = lane >> 4;
  const int mb = blockIdx.x * 64 + wave * 16;
  f32x4 acc[4] = {};
  for (int kt = 0; kt < 32; ++kt) {
    bf16x8 a = *(const bf16x8*)(h1 + (size_t)(mb + lr) * 1024 + kt * 32 + lh * 8);
#pragma unroll
    for (int q = 0; q < 4; ++q) {
      bf16x8 b = *(const bf16x8*)(wo + ((size_t)(q * 32 + kt) * 64 + lane) * 8);
      acc[q] = __builtin_amdgcn_mfma_f32_16x16x32_bf16(a, b, acc[q], 0, 0, 0);
    }
  }
#pragma unroll
  for (int q = 0; q < 4; ++q)
#pragma unroll
    for (int r = 0; r < 4; ++r) {
      int row = mb + lh * 4 + r;
      int col = q * 16 + lr;
      int tt = row >> 6, bi = row & 63;
      float m = (x[bi * 256 + tt] > 0) ? 1.f : 0.f;
      emit[(size_t)row * 64 + col] = (acc[q][r] + bout[col]) * m;
    }
}

// ---------------- CRF forward + gold score, one block per batch element ----------------
__global__ __launch_bounds__(256) void crf_k(const float* __restrict__ emit, const float* __restrict__ trans,
                                             const int* __restrict__ x, const int* __restrict__ y0,
                                             float* __restrict__ out) {
  const int b = blockIdx.x, tid = threadIdx.x;
  __shared__ float tr[4096];
  __shared__ float sc[2][64];
  __shared__ float pm[4][64], ps[4][64];
  __shared__ float redw[4];
  for (int i = tid; i < 4096; i += 256) tr[i] = trans[i];
  if (tid < 64) sc[0][tid] = (tid == 2) ? 0.f : NEGV;  // SOS=2
  __syncthreads();
  {
    const int t = tid;
    const int tag = y0[b * 256 + t];
    const int prev = t ? y0[b * 256 + t - 1] : 2;
    const float m = (x[b * 256 + t] > 0) ? 1.f : 0.f;
    float g = emit[((size_t)t * 64 + b) * 64 + tag] + tr[tag * 64 + prev] * m;
    for (int o = 32; o; o >>= 1) g += __shfl_down(g, o, 64);
    if ((tid & 63) == 0) redw[tid >> 6] = g;
  }
  __syncthreads();
  const float gold = redw[0] + redw[1] + redw[2] + redw[3];
  const int j = tid & 63, kq = tid >> 6;
  int cur = 0;
  for (int t = 0; t < 256; ++t) {
    const float* trj = tr + j * 64 + kq * 16;
    const float* scc = sc[cur] + kq * 16;
    float v[16];
    float mx = -3.0e38f;
#pragma unroll
    for (int k = 0; k < 16; ++k) {
      v[k] = scc[k] + trj[k];
      mx = fmaxf(mx, v[k]);
    }
    float sm = 0.f;
#pragma unroll
    for (int k = 0; k < 16; ++k) sm += __expf(v[k] - mx);
    pm[kq][j] = mx;
    ps[kq][j] = sm;
    __syncthreads();
    if (kq == 0) {
      float M = fmaxf(fmaxf(pm[0][j], pm[1][j]), fmaxf(pm[2][j], pm[3][j]));
      float S = ps[0][j] * __expf(pm[0][j] - M) + ps[1][j] * __expf(pm[1][j] - M) +
                ps[2][j] * __expf(pm[2][j] - M) + ps[3][j] * __expf(pm[3][j] - M);
      float nv = M + __logf(S) + emit[((size_t)t * 64 + b) * 64 + j];
      sc[cur ^ 1][j] = (x[b * 256 + t] > 0) ? nv : sc[cur][j];
    }
    __syncthreads();
    cur ^= 1;
  }
  if (tid < 64) {
    float v2 = sc[cur][tid];
    float M = v2;
    for (int o = 32; o; o >>= 1) M = fmaxf(M, __shfl_xor(M, o, 64));
    float s2 = __expf(v2 - M);
    for (int o = 32; o; o >>= 1) s2 += __shfl_xor(s2, o, 64);
    if (tid == 0) out[b] = M + __logf(s2) - gold;
  }
}

// ---------------- launch ----------------
extern "C" void kernel_launch(void* const* d_in, const int* in_sizes, int n_in, void* d_out, int out_size,
                              void* d_ws, size_t ws_size, hipStream_t stream) {
  (void)in_sizes; (void)n_in; (void)out_size; (void)ws_size;
  const int* x = (const int*)d_in[0];
  const int* y0 = (const int*)d_in[1];
  const float* embed = (const float*)d_in[2];
  const float* Wih0f = (const float*)d_in[3];
  const float* Whh0f = (const float*)d_in[4];
  const float* b0f = (const float*)d_in[5];
  const float* Wih0b = (const float*)d_in[6];
  const float* Whh0b = (const float*)d_in[7];
  const float* b0b = (const float*)d_in[8];
  const float* Wih1f = (const float*)d_in[9];
  const float* Whh1f = (const float*)d_in[10];
  const float* b1f = (const float*)d_in[11];
  const float* Wih1b = (const float*)d_in[12];
  const float* Whh1b = (const float*)d_in[13];
  const float* b1b = (const float*)d_in[14];
  const float* Wout = (const float*)d_in[15];
  const float* bout = (const float*)d_in[16];
  const float* trans = (const float*)d_in[17];

  char* p = (char*)d_ws;
  auto take = [&](size_t n) { char* r = p; p += (n + 255) & ~(size_t)255; return r; };
  unsigned int* flags = (unsigned int*)take(2048 * sizeof(unsigned int));  // [layer][dir*4+part][64]
  bf16* xs = (bf16*)take(16384ull * 320 * 2);
  bf16* preP = (bf16*)take(16384ull * 4096 * 2);
  bf16* h0 = (bf16*)take(16384ull * 1024 * 2);
  bf16* h1 = (bf16*)take(16384ull * 1024 * 2);
  float* emitb = (float*)take(16384ull * 64 * 4);
  bf16* W0B = (bf16*)take(4096ull * 320 * 2);
  bf16* W1B = (bf16*)take(4096ull * 1024 * 2);
  bf16* WhhB = (bf16*)take(4ull * 1048576 * 2);
  bf16* WoB = (bf16*)take(64ull * 1024 * 2);
  float* bias0 = (float*)take(4096 * 4);
  float* bias1 = (float*)take(4096 * 4);

  hipMemsetAsync(flags, 0, 2048 * sizeof(unsigned int), stream);
  hipLaunchKernelGGL(pack_w0, dim3(5120), dim3(256), 0, stream, Wih0f, Wih0b, W0B);
  hipLaunchKernelGGL(pack_whh4, dim3(4096, 4), dim3(256), 0, stream, Whh0f, Whh0b, Whh1f, Whh1b, WhhB);
  hipLaunchKernelGGL(pack_w1, dim3(16384), dim3(256), 0, stream, Wih1f, Wih1b, W1B);
  hipLaunchKernelGGL(pack_wout, dim3(256), dim3(256), 0, stream, Wout, WoB);
  hipLaunchKernelGGL(pack_bias2, dim3(32), dim3(256), 0, stream, b0f, b0b, b1f, b1b, bias0, bias1);
  hipLaunchKernelGGL(embed_k, dim3(20480), dim3(256), 0, stream, x, embed, xs);

  hipLaunchKernelGGL(gemm_nt, dim3(256, 16), dim3(256), 0, stream, xs, W0B, preP, 320, 10);
  {
    const bf16* a0 = preP; const bf16* a1 = WhhB; const float* a2 = bias0; bf16* a3 = h0;
    unsigned int* a4 = flags;  // layer0 flag region
    void* args[] = {&a0, &a1, &a2, &a3, &a4};
    hipLaunchCooperativeKernel((void*)lstm_wav, dim3(32, 2), dim3(256), args, 0, stream);
  }
  hipLaunchKernelGGL(gemm_nt, dim3(256, 16), dim3(256), 0, stream, h0, W1B, preP, 1024, 32);
  {
    const bf16* a0 = preP; const bf16* a1 = WhhB + 2ull * 1048576; const float* a2 = bias1; bf16* a3 = h1;
    unsigned int* a4 = flags + 1024;  // layer1 flag region
    void* args[] = {&a0, &a1, &a2, &a3, &a4};
    hipLaunchCooperativeKernel((void*)lstm_wav, dim3(32, 2), dim3(256), args, 0, stream);
  }
  hipLaunchKernelGGL(emit_k, dim3(256), dim3(256), 0, stream, h1, WoB, bout, x, emitb);
  hipLaunchKernelGGL(crf_k, dim3(64), dim3(256), 0, stream, emitb, trans, x, y0, (float*)d_out);
}

// Round 18
// 2573.907 us; speedup vs baseline: 1.3809x; 1.3809x over previous
//
#include <hip/hip_runtime.h>
#include <hip/hip_bf16.h>

typedef short bf16x4 __attribute__((ext_vector_type(4)));
typedef short bf16x8 __attribute__((ext_vector_type(8)));
typedef float f32x4 __attribute__((ext_vector_type(4)));
typedef __hip_bfloat16 bf16;
typedef unsigned long long ull;

#define NEGV -10000.0f

// Problem dims: B=64, T=256, E=300, H=500, K=64(tags), V=32000
// Padded: Ep=320, Hp=512, layer-1 input 2*Hp=1024, gate width 4096 = 2dir*4gate*512

__device__ __forceinline__ float sigm(float v) { return 1.0f / (1.0f + __expf(-v)); }
__device__ __forceinline__ float tanh_(float v) { float e = __expf(2.0f * v); return 1.0f - 2.0f / (e + 1.0f); }

// async global->LDS, 16B per lane: global src includes per-lane offset, LDS base wave-uniform
__device__ __forceinline__ void async_load16(const bf16* g, const char* l) {
  __builtin_amdgcn_global_load_lds((const __attribute__((address_space(1))) void*)g,
                                   (__attribute__((address_space(3))) void*)l, 16, 0, 0);
}

// ---------------- weight packing into MFMA fragment-linear layout ----------------
// B-frag layout: dst[((nt*Kt + kt)*64 + lane)*8 + u] = B[kt*32 + (lane>>4)*8 + u][nt*16 + (lane&15)]

__global__ __launch_bounds__(256) void pack_w0(const float* __restrict__ wf, const float* __restrict__ wb,
                                               bf16* __restrict__ dst) {
  int idx = blockIdx.x * 256 + threadIdx.x;            // 4096*320 = 1310720
  int u = idx & 7, lane = (idx >> 3) & 63, rem = idx >> 9;
  int kt = rem % 10, nt = rem / 10;
  int n = (nt << 4) + (lane & 15), k = (kt << 5) + ((lane >> 4) << 3) + u;
  int d = n >> 11, g = (n >> 9) & 3, j = n & 511;
  float v = 0.f;
  if (j < 500 && k < 300) v = (d ? wb : wf)[(g * 500 + j) * 300 + k];
  dst[idx] = __float2bfloat16(v);
}

// all 4 recurrent weight matrices in one launch (blockIdx.y selects)
__global__ __launch_bounds__(256) void pack_whh4(const float* __restrict__ w0f, const float* __restrict__ w0b,
                                                 const float* __restrict__ w1f, const float* __restrict__ w1b,
                                                 bf16* __restrict__ dst) {
  const int which = blockIdx.y;
  const float* w = which == 0 ? w0f : which == 1 ? w0b : which == 2 ? w1f : w1b;
  int idx = blockIdx.x * 256 + threadIdx.x;            // 2048*512 = 1048576 per matrix
  int u = idx & 7, lane = (idx >> 3) & 63, rem = idx >> 9;
  int kt = rem & 15, nt = rem >> 4;
  int n = (nt << 4) + (lane & 15), k = (kt << 5) + ((lane >> 4) << 3) + u;
  int g = n >> 9, j = n & 511;
  float v = 0.f;
  if (j < 500 && k < 500) v = w[(g * 500 + j) * 500 + k];
  dst[(size_t)which * 1048576 + idx] = __float2bfloat16(v);
}

__global__ __launch_bounds__(256) void pack_w1(const float* __restrict__ wf, const float* __restrict__ wb,
                                               bf16* __restrict__ dst) {
  int idx = blockIdx.x * 256 + threadIdx.x;            // 4096*1024 = 4194304
  int u = idx & 7, lane = (idx >> 3) & 63, rem = idx >> 9;
  int kt = rem & 31, nt = rem >> 5;
  int n = (nt << 4) + (lane & 15), k = (kt << 5) + ((lane >> 4) << 3) + u;
  int d = n >> 11, g = (n >> 9) & 3, j = n & 511;
  int kk = k & 511;
  int ks = (k < 512) ? kk : 500 + kk;
  float v = 0.f;
  if (j < 500 && kk < 500) v = (d ? wb : wf)[(g * 500 + j) * 1000 + ks];
  dst[idx] = __float2bfloat16(v);
}

__global__ __launch_bounds__(256) void pack_wout(const float* __restrict__ w, bf16* __restrict__ dst) {
  int idx = blockIdx.x * 256 + threadIdx.x;            // 4*32*512 = 65536
  int u = idx & 7, lane = (idx >> 3) & 63, rem = idx >> 9;
  int kt = rem & 31, nt = rem >> 5;
  int n = (nt << 4) + (lane & 15), k = (kt << 5) + ((lane >> 4) << 3) + u;
  int kk = k & 511;
  int ks = (k < 512) ? kk : 500 + kk;
  float v = 0.f;
  if (kk < 500) v = w[n * 1000 + ks];
  dst[idx] = __float2bfloat16(v);
}

// both layers' biases in one launch
__global__ __launch_bounds__(256) void pack_bias2(const float* __restrict__ b0f, const float* __restrict__ b0b,
                                                  const float* __restrict__ b1f, const float* __restrict__ b1b,
                                                  float* __restrict__ dst0, float* __restrict__ dst1) {
  int idx = blockIdx.x * 256 + threadIdx.x;
  int layer = idx >> 12, w = idx & 4095;
  int d = w >> 11, g = (w >> 9) & 3, j = w & 511;
  const float* src = layer ? (d ? b1b : b1f) : (d ? b0b : b0f);
  float v = (j < 500) ? src[g * 500 + j] : 0.f;
  (layer ? dst1 : dst0)[w] = v;
}

// ---------------- embedding gather -> bf16 [T*B][320] ----------------
__global__ __launch_bounds__(256) void embed_k(const int* __restrict__ x, const float* __restrict__ em,
                                               bf16* __restrict__ xs) {
  int idx = blockIdx.x * 256 + threadIdx.x;            // 16384*320
  int e = idx % 320;
  int row = idx / 320;
  int t = row >> 6, b = row & 63;
  float v = 0.f;
  if (e < 300) {
    int xv = x[b * 256 + t];
    v = em[(size_t)xv * 300 + e];
  }
  xs[idx] = __float2bfloat16(v);
}

// ---------------- MFMA GEMM: preP = A[16384][Kdim] @ Bfrag, epilogue scatters into
// per-thread-contiguous lstm consumption layout:
// preP[(((t*2+dir)*32+jb)*4+gate)*1024 + lane*16 + (mt*4+r)]
__global__ __launch_bounds__(256) void gemm_nt(const bf16* __restrict__ A, const bf16* __restrict__ Bf,
                                               bf16* __restrict__ C, int Kdim, int Kt) {
  const int lane = threadIdx.x & 63, wave = threadIdx.x >> 6;
  const int lr = lane & 15, lh = lane >> 4;
  const int mb = blockIdx.x * 64;
  const int ntb = blockIdx.y * 16 + wave * 4;
  f32x4 acc[4][4] = {};
  for (int kt = 0; kt < Kt; ++kt) {
    bf16x8 a[4], b[4];
#pragma unroll
    for (int mt = 0; mt < 4; ++mt)
      a[mt] = *(const bf16x8*)(A + (size_t)(mb + mt * 16 + lr) * Kdim + kt * 32 + lh * 8);
#pragma unroll
    for (int q = 0; q < 4; ++q)
      b[q] = *(const bf16x8*)(Bf + ((size_t)(ntb + q) * Kt + kt) * 512 + lane * 8);
#pragma unroll
    for (int mt = 0; mt < 4; ++mt)
#pragma unroll
      for (int q = 0; q < 4; ++q)
        acc[mt][q] = __builtin_amdgcn_mfma_f32_16x16x32_bf16(a[mt], b[q], acc[mt][q], 0, 0, 0);
  }
  const int t = blockIdx.x;  // rows [mb, mb+64) are exactly timestep t
#pragma unroll
  for (int q = 0; q < 4; ++q) {
    const int colbase = (ntb + q) * 16;
    const int dirq = colbase >> 11, gq = (colbase >> 9) & 3, jbq = (colbase >> 4) & 31;
    unsigned short vals[16];
#pragma unroll
    for (int mt = 0; mt < 4; ++mt)
#pragma unroll
      for (int r = 0; r < 4; ++r) {
        bf16 hb = __float2bfloat16(acc[mt][q][r]);
        vals[mt * 4 + r] = *(unsigned short*)&hb;
      }
    bf16* outp = C + ((((size_t)t * 2 + dirq) * 32 + jbq) * 4 + gq) * 1024 + lane * 16;
    *(bf16x8*)(outp) = *(const bf16x8*)(vals);
    *(bf16x8*)(outp + 8) = *(const bf16x8*)(vals + 8);
  }
}

// ---------------- lstm_pipe: arrival-ordered pipelined staging (quarter-split) ----------------
// grid(32 jb, 2 dir, 4 part), 256 thr (wave=gate). Slice kt (cols kt*32..+31) depends only on
// producers 2kt,2kt+1: as soon as a pair flags, stage its 1KB slice (per-wave private LDS copy,
// no cross-wave barrier) and MFMA it, while still polling for stragglers. Exposed cost drops
// from wait_all+full-stage to wait_last+one-slice. Slices column-rotated by (row>>1)&3 at the
// global source so ds_read_b128 is 2-way (free); wfrag static-indexed via unrolled mask loops.
// R15-verified best: 928-936 us/layer (3.63 us/step), total 2.574 ms.
__global__ __launch_bounds__(256, 1) void lstm_pipe(const bf16* __restrict__ preP, const bf16* __restrict__ whh,
                                                    const float* __restrict__ bias, bf16* __restrict__ hout,
                                                    unsigned int* __restrict__ flags) {
  constexpr int ROWS = 16;
  const int tid = threadIdx.x, lane = tid & 63, wave = tid >> 6;
  const int lr = lane & 15, lh = lane >> 4;
  const int jb = blockIdx.x, dir = blockIdx.y, part = blockIdx.z;
  unsigned int* flg = flags + (dir * 4 + part) * 64;
  unsigned int* myflg = flg + jb;
  __shared__ __align__(64) char hlds[4][16][1024];  // per-wave copy: [wave][kt][16 rows x 64B]
  __shared__ float xch[4 * ROWS * 17];
  __shared__ float cst[ROWS * 16];
  for (int i = tid; i < ROWS * 16; i += 256) cst[i] = 0.f;
  const float bb = bias[dir * 2048 + wave * 512 + jb * 16 + lr];
  const bf16* wbase = whh + ((size_t)(dir * 128 + wave * 32 + jb) * 16) * 512 + lane * 8;

  bf16x8 wfrag[16];
#pragma unroll
  for (int kt = 0; kt < 16; ++kt) wfrag[kt] = *(const bf16x8*)(wbase + kt * 512);

  unsigned short pf[4];
  {
    const int t0 = dir ? 255 : 0;
    *(bf16x4*)pf = *(const bf16x4*)(preP + ((((size_t)t0 * 2 + dir) * 32 + jb) * 4 + wave) * 1024 +
                                    lane * 16 + part * 4);
  }

  // staging geometry: lane covers row=lane>>2, chunk q=lane&3, rotated source column
  const int srow_st = lane >> 2, sq_st = lane & 3;
  const int gchunk = (sq_st + ((srow_st >> 1) & 3)) & 3;
  // read geometry: LDS chunk p holding global chunk lh for row lr
  const int rp = (lh - ((lr >> 1) & 3)) & 3;

  for (int s = 0; s < 256; ++s) {
    const int t = dir ? 255 - s : s;
    f32x4 acc = {};
    if (s > 0) {
      const unsigned int tgt = (unsigned int)s;
      const int tp = dir ? t + 1 : t - 1;
      const bf16* hp = hout + (size_t)tp * 65536 + dir * 512 +
                       (size_t)(part * 16 + srow_st) * 1024 + gchunk * 8;
      unsigned int pend = 0xFFFFu;
      while (pend) {
        unsigned int v = __hip_atomic_load(flg + (lane & 31), __ATOMIC_RELAXED, __HIP_MEMORY_SCOPE_AGENT);
        unsigned int am = (unsigned int)__ballot((int)(v >= tgt));
        unsigned int ready = 0;
#pragma unroll
        for (int j = 0; j < 16; ++j) {
          if (((pend >> j) & 1u) && (((am >> (2 * j)) & 3u) == 3u)) {
            async_load16(hp + j * 32, (const char*)&hlds[wave][j][0] + lane * 16);
            ready |= 1u << j;
          }
        }
        if (ready) {
          asm volatile("s_waitcnt vmcnt(0)" ::: "memory");
#pragma unroll
          for (int j = 0; j < 16; ++j) {
            if ((ready >> j) & 1u) {
              const bf16x8 afr = *(const bf16x8*)(&hlds[wave][j][0] + lr * 64 + rp * 16);
              acc = __builtin_amdgcn_mfma_f32_16x16x32_bf16(afr, wfrag[j], acc, 0, 0, 0);
            }
          }
          pend &= ~ready;
        }
      }
    }
#pragma unroll
    for (int r = 0; r < 4; ++r) {
      bf16 pv; *(unsigned short*)&pv = pf[r];
      xch[(wave * ROWS + lh * 4 + r) * 17 + lr] = acc[r] + bb + __bfloat162float(pv);
    }
    __syncthreads();
    if (tid < ROWS * 8) {  // 128 threads: 256 cells, 2/thread
      const int row = tid >> 3, c0 = (tid & 7) * 2;
      unsigned int pk = 0;
#pragma unroll
      for (int i = 0; i < 2; ++i) {
        int col = c0 + i;
        float gi = xch[(0 * ROWS + row) * 17 + col];
        float gf = xch[(1 * ROWS + row) * 17 + col];
        float gg = xch[(2 * ROWS + row) * 17 + col];
        float go = xch[(3 * ROWS + row) * 17 + col];
        float c = cst[row * 16 + col];
        float cn = sigm(gf) * c + sigm(gi) * tanh_(gg);
        cst[row * 16 + col] = cn;
        bf16 hb = __float2bfloat16(sigm(go) * tanh_(cn));
        pk |= (unsigned int)(*(unsigned short*)&hb) << (16 * i);
      }
      unsigned int* hq =
          (unsigned int*)(hout + ((size_t)t * 64 + part * ROWS + row) * 1024 + dir * 512 + jb * 16 + c0);
      __hip_atomic_store(hq, pk, __ATOMIC_RELAXED, __HIP_MEMORY_SCOPE_AGENT);
    }
    asm volatile("s_waitcnt vmcnt(0)" ::: "memory");
    __syncthreads();
    if (tid == 0)
      __hip_atomic_store(myflg, (unsigned int)(s + 1), __ATOMIC_RELAXED, __HIP_MEMORY_SCOPE_AGENT);
    if (s < 255) {
      const int tn = dir ? t - 1 : t + 1;
      *(bf16x4*)pf = *(const bf16x4*)(preP + ((((size_t)tn * 2 + dir) * 32 + jb) * 4 + wave) * 1024 +
                                      lane * 16 + part * 4);
    }
  }
}

// ---------------- emit projection: emit[16384][64] = h1 @ WoutB + bout, masked ----------------
__global__ __launch_bounds__(256) void emit_k(const bf16* __restrict__ h1, const bf16* __restrict__ wo,
                                              const float* __restrict__ bout, const int* __restrict__ x,
                                              float* __restrict__ emit) {
  const int tid = threadIdx.x, lane = tid & 63, wave = tid >> 6;
  const int lr = lane & 15, lh = lane >> 4;
  const int mb = blockIdx.x * 64 + wave * 16;
  f32x4 acc[4] = {};
  for (int kt = 0; kt < 32; ++kt) {
    bf16x8 a = *(const bf16x8*)(h1 + (size_t)(mb + lr) * 1024 + kt * 32 + lh * 8);
#pragma unroll
    for (int q = 0; q < 4; ++q) {
      bf16x8 b = *(const bf16x8*)(wo + ((size_t)(q * 32 + kt) * 64 + lane) * 8);
      acc[q] = __builtin_amdgcn_mfma_f32_16x16x32_bf16(a, b, acc[q], 0, 0, 0);
    }
  }
#pragma unroll
  for (int q = 0; q < 4; ++q)
#pragma unroll
    for (int r = 0; r < 4; ++r) {
      int row = mb + lh * 4 + r;
      int col = q * 16 + lr;
      int tt = row >> 6, bi = row & 63;
      float m = (x[bi * 256 + tt] > 0) ? 1.f : 0.f;
      emit[(size_t)row * 64 + col] = (acc[q][r] + bout[col]) * m;
    }
}

// ---------------- CRF forward + gold score, one block per batch element ----------------
__global__ __launch_bounds__(256) void crf_k(const float* __restrict__ emit, const float* __restrict__ trans,
                                             const int* __restrict__ x, const int* __restrict__ y0,
                                             float* __restrict__ out) {
  const int b = blockIdx.x, tid = threadIdx.x;
  __shared__ float tr[4096];
  __shared__ float sc[2][64];
  __shared__ float pm[4][64], ps[4][64];
  __shared__ float redw[4];
  for (int i = tid; i < 4096; i += 256) tr[i] = trans[i];
  if (tid < 64) sc[0][tid] = (tid == 2) ? 0.f : NEGV;  // SOS=2
  __syncthreads();
  {
    const int t = tid;
    const int tag = y0[b * 256 + t];
    const int prev = t ? y0[b * 256 + t - 1] : 2;
    const float m = (x[b * 256 + t] > 0) ? 1.f : 0.f;
    float g = emit[((size_t)t * 64 + b) * 64 + tag] + tr[tag * 64 + prev] * m;
    for (int o = 32; o; o >>= 1) g += __shfl_down(g, o, 64);
    if ((tid & 63) == 0) redw[tid >> 6] = g;
  }
  __syncthreads();
  const float gold = redw[0] + redw[1] + redw[2] + redw[3];
  const int j = tid & 63, kq = tid >> 6;
  int cur = 0;
  for (int t = 0; t < 256; ++t) {
    const float* trj = tr + j * 64 + kq * 16;
    const float* scc = sc[cur] + kq * 16;
    float v[16];
    float mx = -3.0e38f;
#pragma unroll
    for (int k = 0; k < 16; ++k) {
      v[k] = scc[k] + trj[k];
      mx = fmaxf(mx, v[k]);
    }
    float sm = 0.f;
#pragma unroll
    for (int k = 0; k < 16; ++k) sm += __expf(v[k] - mx);
    pm[kq][j] = mx;
    ps[kq][j] = sm;
    __syncthreads();
    if (kq == 0) {
      float M = fmaxf(fmaxf(pm[0][j], pm[1][j]), fmaxf(pm[2][j], pm[3][j]));
      float S = ps[0][j] * __expf(pm[0][j] - M) + ps[1][j] * __expf(pm[1][j] - M) +
                ps[2][j] * __expf(pm[2][j] - M) + ps[3][j] * __expf(pm[3][j] - M);
      float nv = M + __logf(S) + emit[((size_t)t * 64 + b) * 64 + j];
      sc[cur ^ 1][j] = (x[b * 256 + t] > 0) ? nv : sc[cur][j];
    }
    __syncthreads();
    cur ^= 1;
  }
  if (tid < 64) {
    float v2 = sc[cur][tid];
    float M = v2;
    for (int o = 32; o; o >>= 1) M = fmaxf(M, __shfl_xor(M, o, 64));
    float s2 = __expf(v2 - M);
    for (int o = 32; o; o >>= 1) s2 += __shfl_xor(s2, o, 64);
    if (tid == 0) out[b] = M + __logf(s2) - gold;
  }
}

// ---------------- launch ----------------
extern "C" void kernel_launch(void* const* d_in, const int* in_sizes, int n_in, void* d_out, int out_size,
                              void* d_ws, size_t ws_size, hipStream_t stream) {
  (void)in_sizes; (void)n_in; (void)out_size; (void)ws_size;
  const int* x = (const int*)d_in[0];
  const int* y0 = (const int*)d_in[1];
  const float* embed = (const float*)d_in[2];
  const float* Wih0f = (const float*)d_in[3];
  const float* Whh0f = (const float*)d_in[4];
  const float* b0f = (const float*)d_in[5];
  const float* Wih0b = (const float*)d_in[6];
  const float* Whh0b = (const float*)d_in[7];
  const float* b0b = (const float*)d_in[8];
  const float* Wih1f = (const float*)d_in[9];
  const float* Whh1f = (const float*)d_in[10];
  const float* b1f = (const float*)d_in[11];
  const float* Wih1b = (const float*)d_in[12];
  const float* Whh1b = (const float*)d_in[13];
  const float* b1b = (const float*)d_in[14];
  const float* Wout = (const float*)d_in[15];
  const float* bout = (const float*)d_in[16];
  const float* trans = (const float*)d_in[17];

  char* p = (char*)d_ws;
  auto take = [&](size_t n) { char* r = p; p += (n + 255) & ~(size_t)255; return r; };
  unsigned int* flags = (unsigned int*)take(2048 * sizeof(unsigned int));  // [layer][group][64]
  bf16* xs = (bf16*)take(16384ull * 320 * 2);
  bf16* preP = (bf16*)take(16384ull * 4096 * 2);
  bf16* h0 = (bf16*)take(16384ull * 1024 * 2);
  bf16* h1 = (bf16*)take(16384ull * 1024 * 2);
  float* emitb = (float*)take(16384ull * 64 * 4);
  bf16* W0B = (bf16*)take(4096ull * 320 * 2);
  bf16* W1B = (bf16*)take(4096ull * 1024 * 2);
  bf16* WhhB = (bf16*)take(4ull * 1048576 * 2);
  bf16* WoB = (bf16*)take(64ull * 1024 * 2);
  float* bias0 = (float*)take(4096 * 4);
  float* bias1 = (float*)take(4096 * 4);

  hipMemsetAsync(flags, 0, 2048 * sizeof(unsigned int), stream);
  hipLaunchKernelGGL(pack_w0, dim3(5120), dim3(256), 0, stream, Wih0f, Wih0b, W0B);
  hipLaunchKernelGGL(pack_whh4, dim3(4096, 4), dim3(256), 0, stream, Whh0f, Whh0b, Whh1f, Whh1b, WhhB);
  hipLaunchKernelGGL(pack_w1, dim3(16384), dim3(256), 0, stream, Wih1f, Wih1b, W1B);
  hipLaunchKernelGGL(pack_wout, dim3(256), dim3(256), 0, stream, Wout, WoB);
  hipLaunchKernelGGL(pack_bias2, dim3(32), dim3(256), 0, stream, b0f, b0b, b1f, b1b, bias0, bias1);
  hipLaunchKernelGGL(embed_k, dim3(20480), dim3(256), 0, stream, x, embed, xs);

  hipLaunchKernelGGL(gemm_nt, dim3(256, 16), dim3(256), 0, stream, xs, W0B, preP, 320, 10);
  {
    const bf16* a0 = preP; const bf16* a1 = WhhB; const float* a2 = bias0; bf16* a3 = h0;
    unsigned int* a4 = flags;  // layer0 flag region
    void* args[] = {&a0, &a1, &a2, &a3, &a4};
    hipLaunchCooperativeKernel((void*)lstm_pipe, dim3(32, 2, 4), dim3(256), args, 0, stream);
  }
  hipLaunchKernelGGL(gemm_nt, dim3(256, 16), dim3(256), 0, stream, h0, W1B, preP, 1024, 32);
  {
    const bf16* a0 = preP; const bf16* a1 = WhhB + 2ull * 1048576; const float* a2 = bias1; bf16* a3 = h1;
    unsigned int* a4 = flags + 1024;  // layer1 flag region
    void* args[] = {&a0, &a1, &a2, &a3, &a4};
    hipLaunchCooperativeKernel((void*)lstm_pipe, dim3(32, 2, 4), dim3(256), args, 0, stream);
  }
  hipLaunchKernelGGL(emit_k, dim3(256), dim3(256), 0, stream, h1, WoB, bout, x, emitb);
  hipLaunchKernelGGL(crf_k, dim3(64), dim3(256), 0, stream, emitb, trans, x, y0, (float*)d_out);
}